// Round 6
// baseline (1333.754 us; speedup 1.0000x reference)
//
#include <hip/hip_runtime.h>
#include <math.h>

#define DEVFN static __device__ __forceinline__

constexpr int Bn = 1024, Dn = 128, Wn = 512, Tn = 8;
constexpr int NSTEP = 48;
constexpr int RPB = 4;            // batch rows per block
constexpr int NBLK = Bn / RPB;    // 256 blocks = 1 per CU
constexpr int NTHR = 1024;        // 16 waves per CU
constexpr int BD = Bn * Dn;

// workspace byte offsets
constexpr size_t OFF_SLOTS = 0;                            // NSTEP doubles
constexpr size_t OFF_CNT   = 512;                          // NSTEP uint32 arrive counters
constexpr size_t OFF_W0T   = 1024;                         // [Dn][Wn] f32
constexpr size_t OFF_W1T   = OFF_W0T + (size_t)Dn*Wn*4;    // [Wn][Wn] f32
constexpr size_t OFF_W2T   = OFF_W1T + (size_t)Wn*Wn*4;    // [Wn][Dn] f32

// Tsit5 tableau (float)
constexpr float A21f = 0.161f;
constexpr float A31f = -0.008480655492356989f, A32f = 0.335480655492357f;
constexpr float A41f = 2.8971530571054935f, A42f = -6.359448489975075f, A43f = 4.3622954328695815f;
constexpr float A51f = 5.325864828439257f, A52f = -11.748883564062828f, A53f = 7.4955393428898365f, A54f = -0.09249506636175525f;
constexpr float A61f = 5.86145544294642f, A62f = -12.92096931784711f, A63f = 8.159367898576159f, A64f = -0.071584973281401f, A65f = -0.028269050394068383f;
constexpr float B1f = 0.09646076681806523f, B2f = 0.01f, B3f = 0.4798896504144996f, B4f = 1.379008574103742f, B5f = -3.290069515436081f, B6f = 2.324710524099774f;
constexpr float E1f = -0.00178001105222577714f, E2f = -0.0008164344596567469f, E3f = 0.007880878010261995f, E4f = -0.1447110071732629f, E5f = 0.5823571654525552f, E6f = -0.45808210592918697f, E7f = 0.015151515151515152f;

DEVFN float softplusf(float x) {
  return fmaxf(x, 0.f) + log1pf(expf(-fabsf(x)));
}

// Dense layer for the block's 4 rows. K-split with INTERLEAVED K-slices:
// replica kg handles float4s at i=(j*KSPL+kg)*4, so one wave's LDS z-reads
// span KSPL*16B contiguous bytes -> bank-conflict-free (<=2-way).
// All K-replicas of a column-group sit in one wave -> butterfly shuffle
// reduce, no LDS partials. Caller must __syncthreads() after.
template<int K, int O, int CPT, bool ACT>
DEVFN void dense_layer(const float* __restrict__ zl, const float* __restrict__ WT,
                       const float* __restrict__ biasl, float* __restrict__ outl,
                       int tid)
{
  constexpr int CG   = O / CPT;        // col-groups
  constexpr int KSPL = NTHR / CG;      // K-split factor
  constexpr int KL   = K / KSPL;       // K per thread
  constexpr int CGW  = 64 / KSPL;      // col-groups per wave
  static_assert(CG * KSPL == NTHR, "mapping");
  static_assert(KSPL * KL == K && (KL % 4) == 0, "ksplit");
  static_assert(CGW * KSPL == 64, "wave");

  const int lane = tid & 63;
  const int wid  = tid >> 6;
  const int cgl  = lane & (CGW - 1);
  const int kg   = lane / CGW;
  const int oc   = (wid * CGW + cgl) * CPT;

  float acc[4][CPT];
#pragma unroll
  for (int r = 0; r < 4; ++r)
#pragma unroll
    for (int c = 0; c < CPT; ++c) acc[r][c] = 0.f;

  const float* wbase = WT + (kg * 4) * O + oc;   // row kg*4, this thread's cols
  constexpr int WSTEP = 4 * KSPL * O;            // advance per j iteration

#pragma unroll 2
  for (int j = 0; j < KL / 4; ++j) {
    const int i = (j * KSPL + kg) * 4;
    float zv[4][4];
#pragma unroll
    for (int r = 0; r < 4; ++r) {
      const float4 t = *(const float4*)&zl[r*K + i];
      zv[r][0] = t.x; zv[r][1] = t.y; zv[r][2] = t.z; zv[r][3] = t.w;
    }
    const float* wr = wbase + j * WSTEP;
#pragma unroll
    for (int ii = 0; ii < 4; ++ii) {
      if constexpr (CPT == 4) {
        const float4 wv = *(const float4*)(wr + ii*O);
#pragma unroll
        for (int r = 0; r < 4; ++r) {
          acc[r][0] = fmaf(zv[r][ii], wv.x, acc[r][0]);
          acc[r][1] = fmaf(zv[r][ii], wv.y, acc[r][1]);
          acc[r][2] = fmaf(zv[r][ii], wv.z, acc[r][2]);
          acc[r][3] = fmaf(zv[r][ii], wv.w, acc[r][3]);
        }
      } else {
        const float2 wv = *(const float2*)(wr + ii*O);
#pragma unroll
        for (int r = 0; r < 4; ++r) {
          acc[r][0] = fmaf(zv[r][ii], wv.x, acc[r][0]);
          acc[r][1] = fmaf(zv[r][ii], wv.y, acc[r][1]);
        }
      }
    }
  }

  // butterfly reduce across KSPL replicas (kg lives on lane bits >= log2(CGW))
#pragma unroll
  for (int m = CGW; m < 64; m <<= 1) {
#pragma unroll
    for (int r = 0; r < 4; ++r)
#pragma unroll
      for (int c = 0; c < CPT; ++c)
        acc[r][c] += __shfl_xor(acc[r][c], m, 64);
  }

  // replicas kg=0..3 each finalize one row (bias + act + LDS write)
  if (kg < 4) {
    const int r = kg;
    if constexpr (CPT == 4) {
      const float4 b4 = *(const float4*)&biasl[oc];
      float4 v;
      v.x = acc[r][0] + b4.x; v.y = acc[r][1] + b4.y;
      v.z = acc[r][2] + b4.z; v.w = acc[r][3] + b4.w;
      if (ACT) {
        v.x = softplusf(v.x); v.y = softplusf(v.y);
        v.z = softplusf(v.z); v.w = softplusf(v.w);
      }
      *(float4*)&outl[r*O + oc] = v;
    } else {
      const float2 b2v = *(const float2*)&biasl[oc];
      float2 v;
      v.x = acc[r][0] + b2v.x; v.y = acc[r][1] + b2v.y;
      if (ACT) { v.x = softplusf(v.x); v.y = softplusf(v.y); }
      *(float2*)&outl[r*O + oc] = v;
    }
  }
}

template<int N>
DEVFN void combine(float* __restrict__ zl, const float* __restrict__ yl, float h,
                   const float* c, const float (*kkl)[RPB*Dn], int tid)
{
  for (int e = tid; e < RPB*Dn; e += NTHR) {
    float a = c[0] * kkl[0][e];
#pragma unroll
    for (int l = 1; l < N; ++l) a = fmaf(c[l], kkl[l][e], a);
    zl[e] = fmaf(h, a, yl[e]);
  }
}

__global__ __launch_bounds__(256) void ode_init(
    const float* __restrict__ y0,
    const float* __restrict__ W0, const float* __restrict__ W1,
    const float* __restrict__ W2, char* __restrict__ ws, float* __restrict__ out)
{
  const int idx = blockIdx.x * blockDim.x + threadIdx.x;
  float* W0T = (float*)(ws + OFF_W0T);
  float* W1T = (float*)(ws + OFF_W1T);
  float* W2T = (float*)(ws + OFF_W2T);
  double* slots = (double*)(ws + OFF_SLOTS);
  unsigned* cnt = (unsigned*)(ws + OFF_CNT);

  if (idx < Tn*BD) out[idx] = (idx < BD) ? y0[idx] : 0.f;  // ys[0]=y0, rest zero
  if (idx < Dn*Wn) { const int i = idx >> 9, o = idx & (Wn-1); W0T[idx] = W0[o*Dn + i]; }
  if (idx < Wn*Wn) { const int i = idx >> 9, o = idx & (Wn-1); W1T[idx] = W1[o*Wn + i]; }
  if (idx < Wn*Dn) { const int i = idx >> 7, o = idx & (Dn-1); W2T[idx] = W2[o*Wn + i]; }
  if (idx < NSTEP) { slots[idx] = 0.0; cnt[idx] = 0u; }
}

// amdgpu_waves_per_eu(4,4): exactly 4 waves/SIMD (the only feasible residency
// for a 1024-thread block) -> VGPR budget 128; stops the allocator's
// spill-for-occupancy heuristic (round-5 WRITE_SIZE ~1 GB = scratch stores).
__attribute__((amdgpu_waves_per_eu(4, 4)))
__global__ __launch_bounds__(NTHR) void ode_persist(
    const float* __restrict__ ts, const float* __restrict__ y0,
    const float* __restrict__ b0, const float* __restrict__ b1,
    const float* __restrict__ b2,
    char* __restrict__ ws, float* __restrict__ out)
{
  const float* W0T = (const float*)(ws + OFF_W0T);
  const float* W1T = (const float*)(ws + OFF_W1T);
  const float* W2T = (const float*)(ws + OFF_W2T);
  double* slots = (double*)(ws + OFF_SLOTS);
  unsigned* cnt = (unsigned*)(ws + OFF_CNT);

  __shared__ __align__(16) float yl[RPB*Dn];        // current y (persistent)
  __shared__ __align__(16) float zl[RPB*Dn];        // stage input / y_new
  __shared__ __align__(16) float h1l[RPB*Wn];
  __shared__ __align__(16) float h2l[RPB*Wn];
  __shared__ __align__(16) float kkl[7][RPB*Dn];    // k1 persists (FSAL)
  __shared__ __align__(16) float b0l[Wn], b1l[Wn], b2l[Dn];
  __shared__ float tsl[Tn];
  __shared__ float wred[NTHR/64];
  __shared__ double ered;

  const int tid  = threadIdx.x;
  const int row0 = blockIdx.x * RPB;

  // ---- one-time setup ----
  for (int e = tid; e < Wn; e += NTHR) { b0l[e] = b0[e]; b1l[e] = b1[e]; }
  for (int e = tid; e < Dn; e += NTHR) b2l[e] = b2[e];
  if (tid < Tn) tsl[tid] = ts[tid];
  {
    const float* yg = y0 + row0*Dn;
    for (int e = tid; e < RPB*Dn; e += NTHR) { const float v = yg[e]; yl[e] = v; zl[e] = v; }
  }
  __syncthreads();

  // bootstrap k1 = f(y0)
  dense_layer<Dn, Wn, 4, true >(zl,  W0T, b0l, h1l, tid); __syncthreads();
  dense_layer<Wn, Wn, 4, true >(h1l, W1T, b1l, h2l, tid); __syncthreads();
  dense_layer<Wn, Dn, 2, false>(h2l, W2T, b2l, kkl[0], tid); __syncthreads();

  int   si = 1;
  float t  = 0.f;
  float dt = tsl[1] - tsl[0];

  for (int s = 0; s < NSTEP; ++s) {
    if (si >= Tn) break;                      // uniform across all blocks
    const int sic = (si < Tn-1) ? si : Tn-1;
    const float tns = tsl[sic];
    const float h = fmaxf(fminf(dt, tns - t), 0.f);

#define EVALF(dst) \
    dense_layer<Dn, Wn, 4, true >(zl,  W0T, b0l, h1l, tid); __syncthreads(); \
    dense_layer<Wn, Wn, 4, true >(h1l, W1T, b1l, h2l, tid); __syncthreads(); \
    dense_layer<Wn, Dn, 2, false>(h2l, W2T, b2l, dst, tid); __syncthreads();

    { const float c[1] = {A21f};
      combine<1>(zl, yl, h, c, kkl, tid); } __syncthreads();
    EVALF(kkl[1])
    { const float c[2] = {A31f, A32f};
      combine<2>(zl, yl, h, c, kkl, tid); } __syncthreads();
    EVALF(kkl[2])
    { const float c[3] = {A41f, A42f, A43f};
      combine<3>(zl, yl, h, c, kkl, tid); } __syncthreads();
    EVALF(kkl[3])
    { const float c[4] = {A51f, A52f, A53f, A54f};
      combine<4>(zl, yl, h, c, kkl, tid); } __syncthreads();
    EVALF(kkl[4])
    { const float c[5] = {A61f, A62f, A63f, A64f, A65f};
      combine<5>(zl, yl, h, c, kkl, tid); } __syncthreads();
    EVALF(kkl[5])
    { const float c[6] = {B1f, B2f, B3f, B4f, B5f, B6f};
      combine<6>(zl, yl, h, c, kkl, tid); } __syncthreads();   // zl = y_new
    EVALF(kkl[6])                                              // k7 = f(y_new)
#undef EVALF

    // error partial sums (this block's 512 elements)
    float local = 0.f;
    for (int e = tid; e < RPB*Dn; e += NTHR) {
      float a = E1f * kkl[0][e];
      a = fmaf(E2f, kkl[1][e], a);
      a = fmaf(E3f, kkl[2][e], a);
      a = fmaf(E4f, kkl[3][e], a);
      a = fmaf(E5f, kkl[4][e], a);
      a = fmaf(E6f, kkl[5][e], a);
      a = fmaf(E7f, kkl[6][e], a);
      const float ev = h * a;
      const float sc = fmaf(1e-3f, fmaxf(fabsf(yl[e]), fabsf(zl[e])), 1e-6f);
      const float q = ev / sc;
      local = fmaf(q, q, local);
    }
#pragma unroll
    for (int off = 32; off > 0; off >>= 1) local += __shfl_down(local, off);
    if ((tid & 63) == 0) wred[tid >> 6] = local;
    __syncthreads();

    // ---- lightweight grid barrier: atomics only, NO cache maintenance ----
    if (tid == 0) {
      float tot = 0.f;
#pragma unroll
      for (int w = 0; w < NTHR/64; ++w) tot += wred[w];
      __hip_atomic_fetch_add(&slots[s], (double)tot,
                             __ATOMIC_RELAXED, __HIP_MEMORY_SCOPE_AGENT);
      __hip_atomic_fetch_add(&cnt[s], 1u,
                             __ATOMIC_RELEASE, __HIP_MEMORY_SCOPE_AGENT);
      while (__hip_atomic_load(&cnt[s], __ATOMIC_RELAXED,
                               __HIP_MEMORY_SCOPE_AGENT) < (unsigned)NBLK)
        __builtin_amdgcn_s_sleep(2);
      union { unsigned long long u; double d; } uv;
      uv.u = __hip_atomic_load((const unsigned long long*)&slots[s],
                               __ATOMIC_RELAXED, __HIP_MEMORY_SCOPE_AGENT);
      ered = uv.d;
    }
    __syncthreads();

    const float enorm = (float)sqrt(ered / (double)BD);
    const bool accept = (enorm <= 1.f);
    const float tnew = t + h;
    const bool hit = accept && (tnew >= tns - 1e-6f);

    if (accept) {
      t = tnew;
      for (int e = tid; e < RPB*Dn; e += NTHR) { yl[e] = zl[e]; kkl[0][e] = kkl[6][e]; }
      if (hit) {
        float* op = out + (size_t)sic*BD + row0*Dn;
        for (int e = tid; e < RPB*Dn; e += NTHR) op[e] = zl[e];
        si += 1;
      }
    }
    {
      const float safe_e = (enorm > 0.f) ? enorm : 1.f;
      const float factor = (enorm > 0.f)
          ? fminf(fmaxf(0.9f * powf(safe_e, -0.2f), 0.2f), 10.f) : 10.f;
      dt *= factor;
    }
    __syncthreads();                          // copies visible before next stage
  }
}

extern "C" void kernel_launch(void* const* d_in, const int* in_sizes, int n_in,
                              void* d_out, int out_size, void* d_ws, size_t ws_size,
                              hipStream_t stream) {
  (void)in_sizes; (void)n_in; (void)out_size; (void)ws_size;
  const float* ts = (const float*)d_in[0];
  const float* y0 = (const float*)d_in[1];
  const float* W0 = (const float*)d_in[2];
  const float* b0 = (const float*)d_in[3];
  const float* W1 = (const float*)d_in[4];
  const float* b1 = (const float*)d_in[5];
  const float* W2 = (const float*)d_in[6];
  const float* b2 = (const float*)d_in[7];
  float* out = (float*)d_out;
  char* ws = (char*)d_ws;

  hipLaunchKernelGGL(ode_init, dim3((Tn*BD)/256), dim3(256), 0, stream,
                     y0, W0, W1, W2, ws, out);

  void* args[] = { (void*)&ts, (void*)&y0, (void*)&b0, (void*)&b1,
                   (void*)&b2, (void*)&ws, (void*)&out };
  (void)hipLaunchCooperativeKernel((const void*)ode_persist, dim3(NBLK), dim3(NTHR),
                                   args, 0, stream);
}

// Round 7
// 1317.767 us; speedup vs baseline: 1.0121x; 1.0121x over previous
//
#include <hip/hip_runtime.h>
#include <math.h>

#define DEVFN static __device__ __forceinline__

constexpr int Bn = 1024, Dn = 128, Wn = 512, Tn = 8;
constexpr int NSTEP = 48;
constexpr int RPB = 4;            // batch rows per block
constexpr int NBLK = Bn / RPB;    // 256 blocks = 1 per CU
constexpr int NTHR = 1024;        // 16 waves per CU
constexpr int BD = Bn * Dn;

// workspace byte offsets
constexpr size_t OFF_SLOTS = 0;                            // NSTEP doubles
constexpr size_t OFF_CNT   = 512;                          // NSTEP uint32 arrive counters
constexpr size_t OFF_W0T   = 1024;                         // [Dn][Wn] f32
constexpr size_t OFF_W1T   = OFF_W0T + (size_t)Dn*Wn*4;    // [Wn][Wn] f32
constexpr size_t OFF_W2T   = OFF_W1T + (size_t)Wn*Wn*4;    // [Wn][Dn] f32

// Tsit5 tableau (float)
constexpr float A21f = 0.161f;
constexpr float A31f = -0.008480655492356989f, A32f = 0.335480655492357f;
constexpr float A41f = 2.8971530571054935f, A42f = -6.359448489975075f, A43f = 4.3622954328695815f;
constexpr float A51f = 5.325864828439257f, A52f = -11.748883564062828f, A53f = 7.4955393428898365f, A54f = -0.09249506636175525f;
constexpr float A61f = 5.86145544294642f, A62f = -12.92096931784711f, A63f = 8.159367898576159f, A64f = -0.071584973281401f, A65f = -0.028269050394068383f;
constexpr float B1f = 0.09646076681806523f, B2f = 0.01f, B3f = 0.4798896504144996f, B4f = 1.379008574103742f, B5f = -3.290069515436081f, B6f = 2.324710524099774f;
constexpr float E1f = -0.00178001105222577714f, E2f = -0.0008164344596567469f, E3f = 0.007880878010261995f, E4f = -0.1447110071732629f, E5f = 0.5823571654525552f, E6f = -0.45808210592918697f, E7f = 0.015151515151515152f;

DEVFN float softplusf(float x) {
  return fmaxf(x, 0.f) + log1pf(expf(-fabsf(x)));
}

// Dense layer for the block's 4 rows, CPT=2 cols/thread (LOW register
// pressure: acc[4][2]=8 + zv[4][4]=16 + float2 weight regs ~ 35 live,
// comfortably under the 64-VGPR allocation -> no scratch spills; rounds 4-6's
// CPT=4 variant spilled ~1 GB of scratch stores per run).
// K-split with INTERLEAVED K-slices: replica kg handles float4s at
// i=(j*KSPL+kg)*4 -> one wave's LDS z-reads span contiguous bytes,
// bank-conflict-free (<=2-way). All K-replicas of a column-group sit in one
// wave -> butterfly shuffle reduce. Caller must __syncthreads() after.
template<int K, int O, bool ACT>
DEVFN void dense_layer(const float* __restrict__ zl, const float* __restrict__ WT,
                       const float* __restrict__ biasl, float* __restrict__ outl,
                       int tid)
{
  constexpr int CPT  = 2;
  constexpr int CG   = O / CPT;        // col-groups
  constexpr int KSPL = NTHR / CG;      // K-split factor (4 or 16)
  constexpr int KL   = K / KSPL;       // K per thread
  constexpr int CGW  = 64 / KSPL;      // col-groups per wave
  static_assert(CG * KSPL == NTHR, "mapping");
  static_assert(KSPL * KL == K && (KL % 4) == 0, "ksplit");
  static_assert(CGW * KSPL == 64, "wave");
  static_assert(KSPL >= 4, "rows");

  const int lane = tid & 63;
  const int wid  = tid >> 6;
  const int cgl  = lane & (CGW - 1);
  const int kg   = lane / CGW;
  const int oc   = (wid * CGW + cgl) * CPT;

  float acc[4][CPT];
#pragma unroll
  for (int r = 0; r < 4; ++r)
#pragma unroll
    for (int c = 0; c < CPT; ++c) acc[r][c] = 0.f;

  const float* wbase = WT + (kg * 4) * O + oc;   // row kg*4, this thread's cols
  constexpr int WSTEP = 4 * KSPL * O;            // advance per j iteration

#pragma unroll 2
  for (int j = 0; j < KL / 4; ++j) {
    const int i = (j * KSPL + kg) * 4;
    float zv[4][4];
#pragma unroll
    for (int r = 0; r < 4; ++r) {
      const float4 t = *(const float4*)&zl[r*K + i];
      zv[r][0] = t.x; zv[r][1] = t.y; zv[r][2] = t.z; zv[r][3] = t.w;
    }
    const float* wr = wbase + j * WSTEP;
#pragma unroll
    for (int ii = 0; ii < 4; ++ii) {
      const float2 wv = *(const float2*)(wr + ii*O);
#pragma unroll
      for (int r = 0; r < 4; ++r) {
        acc[r][0] = fmaf(zv[r][ii], wv.x, acc[r][0]);
        acc[r][1] = fmaf(zv[r][ii], wv.y, acc[r][1]);
      }
    }
  }

  // butterfly reduce across KSPL replicas (kg lives on lane bits >= log2(CGW))
#pragma unroll
  for (int m = CGW; m < 64; m <<= 1) {
#pragma unroll
    for (int r = 0; r < 4; ++r)
#pragma unroll
      for (int c = 0; c < CPT; ++c)
        acc[r][c] += __shfl_xor(acc[r][c], m, 64);
  }

  // replicas kg=0..3 each finalize one row (bias + act + LDS write)
  if (kg < 4) {
    const int r = kg;
    const float2 b2v = *(const float2*)&biasl[oc];
    float2 v;
    v.x = acc[r][0] + b2v.x; v.y = acc[r][1] + b2v.y;
    if (ACT) { v.x = softplusf(v.x); v.y = softplusf(v.y); }
    *(float2*)&outl[r*O + oc] = v;
  }
}

template<int N>
DEVFN void combine(float* __restrict__ zl, const float* __restrict__ yl, float h,
                   const float* c, const float (*kkl)[RPB*Dn], int tid)
{
  for (int e = tid; e < RPB*Dn; e += NTHR) {
    float a = c[0] * kkl[0][e];
#pragma unroll
    for (int l = 1; l < N; ++l) a = fmaf(c[l], kkl[l][e], a);
    zl[e] = fmaf(h, a, yl[e]);
  }
}

__global__ __launch_bounds__(256) void ode_init(
    const float* __restrict__ y0,
    const float* __restrict__ W0, const float* __restrict__ W1,
    const float* __restrict__ W2, char* __restrict__ ws, float* __restrict__ out)
{
  const int idx = blockIdx.x * blockDim.x + threadIdx.x;
  float* W0T = (float*)(ws + OFF_W0T);
  float* W1T = (float*)(ws + OFF_W1T);
  float* W2T = (float*)(ws + OFF_W2T);
  double* slots = (double*)(ws + OFF_SLOTS);
  unsigned* cnt = (unsigned*)(ws + OFF_CNT);

  if (idx < Tn*BD) out[idx] = (idx < BD) ? y0[idx] : 0.f;  // ys[0]=y0, rest zero
  if (idx < Dn*Wn) { const int i = idx >> 9, o = idx & (Wn-1); W0T[idx] = W0[o*Dn + i]; }
  if (idx < Wn*Wn) { const int i = idx >> 9, o = idx & (Wn-1); W1T[idx] = W1[o*Wn + i]; }
  if (idx < Wn*Dn) { const int i = idx >> 7, o = idx & (Dn-1); W2T[idx] = W2[o*Wn + i]; }
  if (idx < NSTEP) { slots[idx] = 0.0; cnt[idx] = 0u; }
}

__global__ __launch_bounds__(NTHR) void ode_persist(
    const float* __restrict__ ts, const float* __restrict__ y0,
    const float* __restrict__ b0, const float* __restrict__ b1,
    const float* __restrict__ b2,
    char* __restrict__ ws, float* __restrict__ out)
{
  const float* W0T = (const float*)(ws + OFF_W0T);
  const float* W1T = (const float*)(ws + OFF_W1T);
  const float* W2T = (const float*)(ws + OFF_W2T);
  double* slots = (double*)(ws + OFF_SLOTS);
  unsigned* cnt = (unsigned*)(ws + OFF_CNT);

  __shared__ __align__(16) float yl[RPB*Dn];        // current y (persistent)
  __shared__ __align__(16) float zl[RPB*Dn];        // stage input / y_new
  __shared__ __align__(16) float h1l[RPB*Wn];
  __shared__ __align__(16) float h2l[RPB*Wn];
  __shared__ __align__(16) float kkl[7][RPB*Dn];    // k1 persists (FSAL)
  __shared__ __align__(16) float b0l[Wn], b1l[Wn], b2l[Dn];
  __shared__ float tsl[Tn];
  __shared__ float wred[NTHR/64];
  __shared__ double ered;

  const int tid  = threadIdx.x;
  const int row0 = blockIdx.x * RPB;

  // ---- one-time setup ----
  for (int e = tid; e < Wn; e += NTHR) { b0l[e] = b0[e]; b1l[e] = b1[e]; }
  for (int e = tid; e < Dn; e += NTHR) b2l[e] = b2[e];
  if (tid < Tn) tsl[tid] = ts[tid];
  {
    const float* yg = y0 + row0*Dn;
    for (int e = tid; e < RPB*Dn; e += NTHR) { const float v = yg[e]; yl[e] = v; zl[e] = v; }
  }
  __syncthreads();

  // bootstrap k1 = f(y0)
  dense_layer<Dn, Wn, true >(zl,  W0T, b0l, h1l, tid); __syncthreads();
  dense_layer<Wn, Wn, true >(h1l, W1T, b1l, h2l, tid); __syncthreads();
  dense_layer<Wn, Dn, false>(h2l, W2T, b2l, kkl[0], tid); __syncthreads();

  int   si = 1;
  float t  = 0.f;
  float dt = tsl[1] - tsl[0];

  for (int s = 0; s < NSTEP; ++s) {
    if (si >= Tn) break;                      // uniform across all blocks
    const int sic = (si < Tn-1) ? si : Tn-1;
    const float tns = tsl[sic];
    const float h = fmaxf(fminf(dt, tns - t), 0.f);

#define EVALF(dst) \
    dense_layer<Dn, Wn, true >(zl,  W0T, b0l, h1l, tid); __syncthreads(); \
    dense_layer<Wn, Wn, true >(h1l, W1T, b1l, h2l, tid); __syncthreads(); \
    dense_layer<Wn, Dn, false>(h2l, W2T, b2l, dst, tid); __syncthreads();

    { const float c[1] = {A21f};
      combine<1>(zl, yl, h, c, kkl, tid); } __syncthreads();
    EVALF(kkl[1])
    { const float c[2] = {A31f, A32f};
      combine<2>(zl, yl, h, c, kkl, tid); } __syncthreads();
    EVALF(kkl[2])
    { const float c[3] = {A41f, A42f, A43f};
      combine<3>(zl, yl, h, c, kkl, tid); } __syncthreads();
    EVALF(kkl[3])
    { const float c[4] = {A51f, A52f, A53f, A54f};
      combine<4>(zl, yl, h, c, kkl, tid); } __syncthreads();
    EVALF(kkl[4])
    { const float c[5] = {A61f, A62f, A63f, A64f, A65f};
      combine<5>(zl, yl, h, c, kkl, tid); } __syncthreads();
    EVALF(kkl[5])
    { const float c[6] = {B1f, B2f, B3f, B4f, B5f, B6f};
      combine<6>(zl, yl, h, c, kkl, tid); } __syncthreads();   // zl = y_new
    EVALF(kkl[6])                                              // k7 = f(y_new)
#undef EVALF

    // error partial sums (this block's 512 elements)
    float local = 0.f;
    for (int e = tid; e < RPB*Dn; e += NTHR) {
      float a = E1f * kkl[0][e];
      a = fmaf(E2f, kkl[1][e], a);
      a = fmaf(E3f, kkl[2][e], a);
      a = fmaf(E4f, kkl[3][e], a);
      a = fmaf(E5f, kkl[4][e], a);
      a = fmaf(E6f, kkl[5][e], a);
      a = fmaf(E7f, kkl[6][e], a);
      const float ev = h * a;
      const float sc = fmaf(1e-3f, fmaxf(fabsf(yl[e]), fabsf(zl[e])), 1e-6f);
      const float q = ev / sc;
      local = fmaf(q, q, local);
    }
#pragma unroll
    for (int off = 32; off > 0; off >>= 1) local += __shfl_down(local, off);
    if ((tid & 63) == 0) wred[tid >> 6] = local;
    __syncthreads();

    // ---- lightweight grid barrier: atomics only, NO cache maintenance ----
    // Cross-block data is ONLY slots[s] (device-scope atomics at the
    // coherence point). y/k live in LDS; out rows are block-private.
    if (tid == 0) {
      float tot = 0.f;
#pragma unroll
      for (int w = 0; w < NTHR/64; ++w) tot += wred[w];
      __hip_atomic_fetch_add(&slots[s], (double)tot,
                             __ATOMIC_RELAXED, __HIP_MEMORY_SCOPE_AGENT);
      __hip_atomic_fetch_add(&cnt[s], 1u,
                             __ATOMIC_RELEASE, __HIP_MEMORY_SCOPE_AGENT);
      while (__hip_atomic_load(&cnt[s], __ATOMIC_RELAXED,
                               __HIP_MEMORY_SCOPE_AGENT) < (unsigned)NBLK)
        __builtin_amdgcn_s_sleep(2);
      union { unsigned long long u; double d; } uv;
      uv.u = __hip_atomic_load((const unsigned long long*)&slots[s],
                               __ATOMIC_RELAXED, __HIP_MEMORY_SCOPE_AGENT);
      ered = uv.d;
    }
    __syncthreads();

    const float enorm = (float)sqrt(ered / (double)BD);
    const bool accept = (enorm <= 1.f);
    const float tnew = t + h;
    const bool hit = accept && (tnew >= tns - 1e-6f);

    if (accept) {
      t = tnew;
      for (int e = tid; e < RPB*Dn; e += NTHR) { yl[e] = zl[e]; kkl[0][e] = kkl[6][e]; }
      if (hit) {
        float* op = out + (size_t)sic*BD + row0*Dn;
        for (int e = tid; e < RPB*Dn; e += NTHR) op[e] = zl[e];
        si += 1;
      }
    }
    {
      const float safe_e = (enorm > 0.f) ? enorm : 1.f;
      const float factor = (enorm > 0.f)
          ? fminf(fmaxf(0.9f * powf(safe_e, -0.2f), 0.2f), 10.f) : 10.f;
      dt *= factor;
    }
    __syncthreads();                          // copies visible before next stage
  }
}

extern "C" void kernel_launch(void* const* d_in, const int* in_sizes, int n_in,
                              void* d_out, int out_size, void* d_ws, size_t ws_size,
                              hipStream_t stream) {
  (void)in_sizes; (void)n_in; (void)out_size; (void)ws_size;
  const float* ts = (const float*)d_in[0];
  const float* y0 = (const float*)d_in[1];
  const float* W0 = (const float*)d_in[2];
  const float* b0 = (const float*)d_in[3];
  const float* W1 = (const float*)d_in[4];
  const float* b1 = (const float*)d_in[5];
  const float* W2 = (const float*)d_in[6];
  const float* b2 = (const float*)d_in[7];
  float* out = (float*)d_out;
  char* ws = (char*)d_ws;

  hipLaunchKernelGGL(ode_init, dim3((Tn*BD)/256), dim3(256), 0, stream,
                     y0, W0, W1, W2, ws, out);

  void* args[] = { (void*)&ts, (void*)&y0, (void*)&b0, (void*)&b1,
                   (void*)&b2, (void*)&ws, (void*)&out };
  (void)hipLaunchCooperativeKernel((const void*)ode_persist, dim3(NBLK), dim3(NTHR),
                                   args, 0, stream);
}